// Round 7
// baseline (893.822 us; speedup 1.0000x reference)
//
#include <hip/hip_runtime.h>
#include <stdint.h>

#define RELS 8
#define F 256
#define KDIM 2304        // 8*256 stacked relations + 256 root/self columns
#define SCAN_CHUNK 1024  // bins per scan1 block (256 threads x 4)

typedef __attribute__((ext_vector_type(8))) short short8;
typedef __attribute__((ext_vector_type(4))) float f32x4;
typedef __attribute__((ext_vector_type(2))) unsigned int uint2v;

__device__ __forceinline__ unsigned short f2bf(float f) {
  union { float f; unsigned int u; } v; v.f = f;
  unsigned int u = v.u;
  if ((u & 0x7f800000u) == 0x7f800000u) return (unsigned short)(u >> 16);
  return (unsigned short)((u + 0x7fffu + ((u >> 16) & 1u)) >> 16);  // RNE
}
__device__ __forceinline__ float bf2f(unsigned short b) {
  union { unsigned int u; float f; } v; v.u = ((unsigned int)b) << 16; return v.f;
}

// ---- x fp32 -> compact bf16 [N,256] (small L3-resident gather source)
__global__ void k_xb(const float* __restrict__ x, unsigned short* __restrict__ xb, int N) {
  int tid = blockIdx.x * blockDim.x + threadIdx.x;
  int n = tid >> 6, q = tid & 63;
  if (n >= N) return;
  const float4 v = *(const float4*)&x[(size_t)n * F + q * 4];
  ushort4 o;
  o.x = f2bf(v.x); o.y = f2bf(v.y); o.z = f2bf(v.z); o.w = f2bf(v.w);
  *(ushort4*)&xb[(size_t)n * F + q * 4] = o;
}

// ---- weight convert + transpose:  Wt[n][k] = bf16( k<2048 ? W[k][n] : root[k-2048][n] )
__global__ void k_wt(const float* __restrict__ W, const float* __restrict__ root,
                     unsigned short* __restrict__ Wt, int Ncols) {
  int tid = blockIdx.x * blockDim.x + threadIdx.x;
  int total = Ncols * KDIM;
  if (tid >= total) return;
  int n = tid / KDIM, k = tid - n * KDIM;
  float v = (k < 2048) ? W[(size_t)k * Ncols + n] : root[(size_t)(k - 2048) * Ncols + n];
  Wt[(size_t)n * KDIM + k] = f2bf(v);
}

// ---- CSR build ----
__global__ void k_count(const int* __restrict__ ei, const int* __restrict__ et,
                        int* __restrict__ cnt, int E) {
  int e = blockIdx.x * blockDim.x + threadIdx.x;
  if (e >= E) return;
  int bin = ei[E + e] * RELS + et[e];
  atomicAdd(&cnt[bin], 1);
}

__global__ void k_scan1(const int* __restrict__ cnt, int* __restrict__ start,
                        int* __restrict__ bsum, int nb) {
  __shared__ int tsum[256];
  const int t = threadIdx.x;
  const int idx = blockIdx.x * SCAN_CHUNK + t * 4;
  int v[4]; int s = 0;
#pragma unroll
  for (int i = 0; i < 4; i++) { v[i] = (idx + i < nb) ? cnt[idx + i] : 0; s += v[i]; }
  tsum[t] = s;
  __syncthreads();
  for (int d = 1; d < 256; d <<= 1) {
    int a = (t >= d) ? tsum[t - d] : 0;
    __syncthreads();
    tsum[t] += a;
    __syncthreads();
  }
  int ex = (t > 0) ? tsum[t - 1] : 0;
#pragma unroll
  for (int i = 0; i < 4; i++) { if (idx + i < nb) start[idx + i] = ex; ex += v[i]; }
  if (t == 255) bsum[blockIdx.x] = tsum[255];
}

__global__ void k_scan2(int* __restrict__ bsum, int nblocks) {
  __shared__ int sh[1024];
  const int t = threadIdx.x;
  sh[t] = (t < nblocks) ? bsum[t] : 0;
  __syncthreads();
  for (int d = 1; d < 1024; d <<= 1) {
    int a = (t >= d) ? sh[t - d] : 0;
    __syncthreads();
    sh[t] += a;
    __syncthreads();
  }
  if (t < nblocks) bsum[t] = (t > 0) ? sh[t - 1] : 0;
  if (t == 1023) bsum[nblocks] = sh[1023];
}

__global__ void k_scan3(int* __restrict__ start, const int* __restrict__ bsum,
                        int nb, int nblocks) {
  int i = blockIdx.x * blockDim.x + threadIdx.x;
  if (i < nb) start[i] += bsum[i >> 10];
  if (i == 0) start[nb] = bsum[nblocks];
}

__global__ void k_scatter(const int* __restrict__ ei, const int* __restrict__ et,
                          const int* __restrict__ start, int* __restrict__ cur,
                          int* __restrict__ ssrc, int E) {
  int e = blockIdx.x * blockDim.x + threadIdx.x;
  if (e >= E) return;
  int bin = ei[E + e] * RELS + et[e];
  int p = atomicAdd(&cur[bin], 1);
  ssrc[start[bin] + p] = ei[e];
}

// ---- aggregation: one wave per (dst, rel) bin; 64 lanes cover 256 features ----
__global__ void k_agg(const unsigned short* __restrict__ src,
                      const int* __restrict__ start, const int* __restrict__ ssrc,
                      unsigned short* __restrict__ A, int nbins) {
  int w = blockIdx.x * 4 + (threadIdx.x >> 6);
  int lane = threadIdx.x & 63;
  if (w >= nbins) return;
  int s0 = start[w], s1 = start[w + 1];
  int deg = s1 - s0;
  float scale = 1.0f / (float)(deg > 1 ? deg : 1);
  float a0 = 0.f, a1 = 0.f, a2 = 0.f, a3 = 0.f;
  int e = s0;
  for (; e + 1 < s1; e += 2) {           // 2 outstanding gathers per wave
    int sA = ssrc[e], sB = ssrc[e + 1];
    const ushort4 vA = *(const ushort4*)&src[(size_t)sA * F + lane * 4];
    const ushort4 vB = *(const ushort4*)&src[(size_t)sB * F + lane * 4];
    a0 += bf2f(vA.x) + bf2f(vB.x); a1 += bf2f(vA.y) + bf2f(vB.y);
    a2 += bf2f(vA.z) + bf2f(vB.z); a3 += bf2f(vA.w) + bf2f(vB.w);
  }
  if (e < s1) {
    int sA = ssrc[e];
    const ushort4 vA = *(const ushort4*)&src[(size_t)sA * F + lane * 4];
    a0 += bf2f(vA.x); a1 += bf2f(vA.y); a2 += bf2f(vA.z); a3 += bf2f(vA.w);
  }
  int n = w >> 3, r = w & 7;
  uint2v o;
  o.x = (unsigned)f2bf(a0 * scale) | ((unsigned)f2bf(a1 * scale) << 16);
  o.y = (unsigned)f2bf(a2 * scale) | ((unsigned)f2bf(a3 * scale) << 16);
  __builtin_nontemporal_store(o, (uint2v*)&A[(size_t)n * KDIM + r * F + lane * 4]);
}

// ---- copy self features (compact bf16) into the last 256 K-columns of A (nt) ----
__global__ void k_copy_nt(const unsigned short* __restrict__ src, unsigned short* __restrict__ A, int N) {
  int tid = blockIdx.x * blockDim.x + threadIdx.x;
  int n = tid >> 6, q = tid & 63;
  if (n >= N) return;
  const uint2v v = *(const uint2v*)&src[(size_t)n * F + q * 4];
  __builtin_nontemporal_store(v, (uint2v*)&A[(size_t)n * KDIM + 2048 + q * 4]);
}

// ---- 128x128 MFMA GEMM, register-direct (no LDS, no barriers) ----
// Each lane loads its MFMA fragment straight from global: fragments are
// contiguous 16B runs (A[row][k..k+8]). B panel (<=1.2 MB) is L2-resident;
// A's 2-wave duplicate reads are absorbed by L1/L2/L3 (HBM fetch stays ~1 pass).
// K-loop is barrier-free and 2-stage software-pipelined.
template<bool RELU, bool OUTBF16>
__global__ __launch_bounds__(256) void k_gemm(
    const unsigned short* __restrict__ Ag, const unsigned short* __restrict__ Bg,
    const float* __restrict__ bias, void* __restrict__ outp,
    int Nld, int Mreal) {
  const int t = threadIdx.x;
  const int m0 = blockIdx.x * 128;
  const int n0 = blockIdx.y * 128;
  const int lane = t & 63, wid = t >> 6;
  const int wm = (wid >> 1) * 64, wn = (wid & 1) * 64;
  const int c15 = lane & 15, quad = lane >> 4;

  f32x4 acc[4][4];
#pragma unroll
  for (int i = 0; i < 4; i++)
#pragma unroll
    for (int j = 0; j < 4; j++) acc[i][j] = (f32x4)0.f;

  const unsigned short* ap = Ag + (size_t)(m0 + wm + c15) * KDIM + quad * 8;
  const unsigned short* bp = Bg + (size_t)(n0 + wn + c15) * KDIM + quad * 8;

  short8 sa0[4], sb0[4], sa1[4], sb1[4];
#define LDFRAGS(kt, sa, sb)                                              \
  _Pragma("unroll")                                                      \
  for (int i = 0; i < 4; i++) {                                          \
    sa[i] = *(const short8*)(ap + (size_t)i * 16 * KDIM + (kt));         \
    sb[i] = *(const short8*)(bp + (size_t)i * 16 * KDIM + (kt));         \
  }
#define DOMFMA(sa, sb)                                                   \
  _Pragma("unroll")                                                      \
  for (int mi = 0; mi < 4; mi++)                                         \
    _Pragma("unroll")                                                    \
    for (int ni = 0; ni < 4; ni++)                                       \
      acc[mi][ni] = __builtin_amdgcn_mfma_f32_16x16x32_bf16(sa[mi], sb[ni], acc[mi][ni], 0, 0, 0);

  LDFRAGS(0, sa0, sb0);
  for (int kt = 0; kt < KDIM; kt += 64) {     // KDIM = 36 * 64
    LDFRAGS(kt + 32, sa1, sb1);               // kt+32 <= 2272 < KDIM: always valid
    DOMFMA(sa0, sb0);
    if (kt + 64 < KDIM) { LDFRAGS(kt + 64, sa0, sb0); }
    DOMFMA(sa1, sb1);
  }
#undef LDFRAGS
#undef DOMFMA

#pragma unroll
  for (int mi = 0; mi < 4; mi++) {
#pragma unroll
    for (int ni = 0; ni < 4; ni++) {
      int n = n0 + wn + ni * 16 + c15;
      float bv = bias[n];
#pragma unroll
      for (int r = 0; r < 4; r++) {
        int m = m0 + wm + mi * 16 + quad * 4 + r;
        if (m < Mreal) {
          float v = acc[mi][ni][r] + bv;
          if (RELU) v = v > 0.f ? v : 0.f;
          if (OUTBF16) ((unsigned short*)outp)[(size_t)m * Nld + n] = f2bf(v);
          else         ((float*)outp)[(size_t)m * Nld + n] = v;
        }
      }
    }
  }
}

extern "C" void kernel_launch(void* const* d_in, const int* in_sizes, int n_in,
                              void* d_out, int out_size, void* d_ws, size_t ws_size,
                              hipStream_t stream) {
  const float* x     = (const float*)d_in[0];
  const int*   ei    = (const int*)d_in[1];   // [2, E]: src row then dst row
  const int*   et    = (const int*)d_in[2];   // [E]
  const float* W1    = (const float*)d_in[3]; // [2048,256]
  const float* root1 = (const float*)d_in[4]; // [256,256]
  const float* b1    = (const float*)d_in[5];
  const float* W2    = (const float*)d_in[6]; // [2048,128]
  const float* root2 = (const float*)d_in[7]; // [256,128]
  const float* b2    = (const float*)d_in[8];

  const int N = in_sizes[0] / F;              // 50000
  const int E = in_sizes[2];                  // 800000
  const int nbins = N * RELS;                 // 400000
  const int Mpad = ((N + 127) / 128) * 128;   // 50048
  const int nsb = (nbins + SCAN_CHUNK - 1) / SCAN_CHUNK;

  char* base = (char*)d_ws;
  size_t off = 0;
  auto alloc = [&](size_t bytes) {
    void* r = base + off;
    off = (off + bytes + 511) & ~(size_t)511;
    return r;
  };
  unsigned short* Wt1  = (unsigned short*)alloc((size_t)256 * KDIM * 2);
  unsigned short* Wt2  = (unsigned short*)alloc((size_t)128 * KDIM * 2);
  int*            cnt  = (int*)alloc((size_t)nbins * 4);
  int*            strt = (int*)alloc((size_t)(nbins + 1) * 4);
  int*            bsum = (int*)alloc((size_t)(nsb + 1) * 4);
  int*            ssrc = (int*)alloc((size_t)E * 4);
  // xh: single buffer aliased across lifetimes — layer-1 gather source
  // (bf16 x), then overwritten by GEMM1 as h, then layer-2 gather source.
  unsigned short* xh   = (unsigned short*)alloc((size_t)Mpad * F * 2);
  unsigned short* A    = (unsigned short*)alloc((size_t)Mpad * KDIM * 2);
  (void)ws_size; (void)n_in; (void)out_size;

  hipMemsetAsync(cnt, 0, (size_t)nbins * 4, stream);
  k_xb<<<(N * 64 + 255) / 256, 256, 0, stream>>>(x, xh, N);
  k_wt<<<(256 * KDIM + 255) / 256, 256, 0, stream>>>(W1, root1, Wt1, 256);
  k_wt<<<(128 * KDIM + 255) / 256, 256, 0, stream>>>(W2, root2, Wt2, 128);
  k_count<<<(E + 255) / 256, 256, 0, stream>>>(ei, et, cnt, E);
  k_scan1<<<nsb, 256, 0, stream>>>(cnt, strt, bsum, nbins);
  k_scan2<<<1, 1024, 0, stream>>>(bsum, nsb);
  k_scan3<<<(nbins + 255) / 256, 256, 0, stream>>>(strt, bsum, nbins, nsb);
  hipMemsetAsync(cnt, 0, (size_t)nbins * 4, stream);  // reuse as cursor
  k_scatter<<<(E + 255) / 256, 256, 0, stream>>>(ei, et, strt, cnt, ssrc, E);

  // Layer 1: gather from compact xh (bf16 x); A written nontemporal.
  // GEMM1 then overwrites xh with h (xh's x-copy is dead by that point).
  k_agg<<<(nbins + 3) / 4, 256, 0, stream>>>(xh, strt, ssrc, A, nbins);
  k_copy_nt<<<(N * 64 + 255) / 256, 256, 0, stream>>>(xh, A, N);
  k_gemm<true, true><<<dim3(Mpad / 128, 2), 256, 0, stream>>>(A, Wt1, b1, xh, 256, N);

  // Layer 2: gather from compact xh (now h).
  k_agg<<<(nbins + 3) / 4, 256, 0, stream>>>(xh, strt, ssrc, A, nbins);
  k_copy_nt<<<(N * 64 + 255) / 256, 256, 0, stream>>>(xh, A, N);
  k_gemm<false, false><<<dim3(Mpad / 128, 1), 256, 0, stream>>>(A, Wt2, b2, d_out, 128, N);
}

// Round 8
// 657.421 us; speedup vs baseline: 1.3596x; 1.3596x over previous
//
#include <hip/hip_runtime.h>
#include <stdint.h>

#define RELS 8
#define F 256
#define KDIM 2304        // 8*256 stacked relations + 256 root/self columns
#define SCAN_CHUNK 1024  // bins per scan1 block (256 threads x 4)

typedef __attribute__((ext_vector_type(8))) short short8;
typedef __attribute__((ext_vector_type(4))) float f32x4;
typedef __attribute__((ext_vector_type(2))) unsigned int uint2v;

__device__ __forceinline__ unsigned short f2bf(float f) {
  union { float f; unsigned int u; } v; v.f = f;
  unsigned int u = v.u;
  if ((u & 0x7f800000u) == 0x7f800000u) return (unsigned short)(u >> 16);
  return (unsigned short)((u + 0x7fffu + ((u >> 16) & 1u)) >> 16);  // RNE
}
__device__ __forceinline__ float bf2f(unsigned short b) {
  union { unsigned int u; float f; } v; v.u = ((unsigned int)b) << 16; return v.f;
}

// async 16B global -> LDS (wave-uniform base + lane*16)
#define GLOAD_LDS16(g, l)                                              \
  __builtin_amdgcn_global_load_lds(                                    \
      (const __attribute__((address_space(1))) void*)(g),              \
      (__attribute__((address_space(3))) void*)(l), 16, 0, 0)

// ---- x fp32 -> compact bf16 [N,256] (small L3-resident gather source)
__global__ void k_xb(const float* __restrict__ x, unsigned short* __restrict__ xb, int N) {
  int tid = blockIdx.x * blockDim.x + threadIdx.x;
  int n = tid >> 6, q = tid & 63;
  if (n >= N) return;
  const float4 v = *(const float4*)&x[(size_t)n * F + q * 4];
  ushort4 o;
  o.x = f2bf(v.x); o.y = f2bf(v.y); o.z = f2bf(v.z); o.w = f2bf(v.w);
  *(ushort4*)&xb[(size_t)n * F + q * 4] = o;
}

// ---- weight convert + transpose:  Wt[n][k] = bf16( k<2048 ? W[k][n] : root[k-2048][n] )
__global__ void k_wt(const float* __restrict__ W, const float* __restrict__ root,
                     unsigned short* __restrict__ Wt, int Ncols) {
  int tid = blockIdx.x * blockDim.x + threadIdx.x;
  int total = Ncols * KDIM;
  if (tid >= total) return;
  int n = tid / KDIM, k = tid - n * KDIM;
  float v = (k < 2048) ? W[(size_t)k * Ncols + n] : root[(size_t)(k - 2048) * Ncols + n];
  Wt[(size_t)n * KDIM + k] = f2bf(v);
}

// ---- CSR build ----
__global__ void k_count(const int* __restrict__ ei, const int* __restrict__ et,
                        int* __restrict__ cnt, int E) {
  int e = blockIdx.x * blockDim.x + threadIdx.x;
  if (e >= E) return;
  int bin = ei[E + e] * RELS + et[e];
  atomicAdd(&cnt[bin], 1);
}

__global__ void k_scan1(const int* __restrict__ cnt, int* __restrict__ start,
                        int* __restrict__ bsum, int nb) {
  __shared__ int tsum[256];
  const int t = threadIdx.x;
  const int idx = blockIdx.x * SCAN_CHUNK + t * 4;
  int v[4]; int s = 0;
#pragma unroll
  for (int i = 0; i < 4; i++) { v[i] = (idx + i < nb) ? cnt[idx + i] : 0; s += v[i]; }
  tsum[t] = s;
  __syncthreads();
  for (int d = 1; d < 256; d <<= 1) {
    int a = (t >= d) ? tsum[t - d] : 0;
    __syncthreads();
    tsum[t] += a;
    __syncthreads();
  }
  int ex = (t > 0) ? tsum[t - 1] : 0;
#pragma unroll
  for (int i = 0; i < 4; i++) { if (idx + i < nb) start[idx + i] = ex; ex += v[i]; }
  if (t == 255) bsum[blockIdx.x] = tsum[255];
}

__global__ void k_scan2(int* __restrict__ bsum, int nblocks) {
  __shared__ int sh[1024];
  const int t = threadIdx.x;
  sh[t] = (t < nblocks) ? bsum[t] : 0;
  __syncthreads();
  for (int d = 1; d < 1024; d <<= 1) {
    int a = (t >= d) ? sh[t - d] : 0;
    __syncthreads();
    sh[t] += a;
    __syncthreads();
  }
  if (t < nblocks) bsum[t] = (t > 0) ? sh[t - 1] : 0;
  if (t == 1023) bsum[nblocks] = sh[1023];
}

__global__ void k_scan3(int* __restrict__ start, const int* __restrict__ bsum,
                        int nb, int nblocks) {
  int i = blockIdx.x * blockDim.x + threadIdx.x;
  if (i < nb) start[i] += bsum[i >> 10];
  if (i == 0) start[nb] = bsum[nblocks];
}

__global__ void k_scatter(const int* __restrict__ ei, const int* __restrict__ et,
                          const int* __restrict__ start, int* __restrict__ cur,
                          int* __restrict__ ssrc, int E) {
  int e = blockIdx.x * blockDim.x + threadIdx.x;
  if (e >= E) return;
  int bin = ei[E + e] * RELS + et[e];
  int p = atomicAdd(&cur[bin], 1);
  ssrc[start[bin] + p] = ei[e];
}

// ---- aggregation: one wave per (dst, rel) bin; 64 lanes cover 256 features ----
__global__ void k_agg(const unsigned short* __restrict__ src,
                      const int* __restrict__ start, const int* __restrict__ ssrc,
                      unsigned short* __restrict__ A, int nbins) {
  int w = blockIdx.x * 4 + (threadIdx.x >> 6);
  int lane = threadIdx.x & 63;
  if (w >= nbins) return;
  int s0 = start[w], s1 = start[w + 1];
  int deg = s1 - s0;
  float scale = 1.0f / (float)(deg > 1 ? deg : 1);
  float a0 = 0.f, a1 = 0.f, a2 = 0.f, a3 = 0.f;
  int e = s0;
  for (; e + 1 < s1; e += 2) {           // 2 outstanding gathers per wave
    int sA = ssrc[e], sB = ssrc[e + 1];
    const ushort4 vA = *(const ushort4*)&src[(size_t)sA * F + lane * 4];
    const ushort4 vB = *(const ushort4*)&src[(size_t)sB * F + lane * 4];
    a0 += bf2f(vA.x) + bf2f(vB.x); a1 += bf2f(vA.y) + bf2f(vB.y);
    a2 += bf2f(vA.z) + bf2f(vB.z); a3 += bf2f(vA.w) + bf2f(vB.w);
  }
  if (e < s1) {
    int sA = ssrc[e];
    const ushort4 vA = *(const ushort4*)&src[(size_t)sA * F + lane * 4];
    a0 += bf2f(vA.x); a1 += bf2f(vA.y); a2 += bf2f(vA.z); a3 += bf2f(vA.w);
  }
  int n = w >> 3, r = w & 7;
  uint2v o;
  o.x = (unsigned)f2bf(a0 * scale) | ((unsigned)f2bf(a1 * scale) << 16);
  o.y = (unsigned)f2bf(a2 * scale) | ((unsigned)f2bf(a3 * scale) << 16);
  __builtin_nontemporal_store(o, (uint2v*)&A[(size_t)n * KDIM + r * F + lane * 4]);
}

// ---- copy self features (compact bf16) into the last 256 K-columns of A (nt) ----
__global__ void k_copy_nt(const unsigned short* __restrict__ src, unsigned short* __restrict__ A, int N) {
  int tid = blockIdx.x * blockDim.x + threadIdx.x;
  int n = tid >> 6, q = tid & 63;
  if (n >= N) return;
  const uint2v v = *(const uint2v*)&src[(size_t)n * F + q * 4];
  __builtin_nontemporal_store(v, (uint2v*)&A[(size_t)n * KDIM + 2048 + q * 4]);
}

// ---- 128x128 bf16 MFMA GEMM, BK=64:  out = A[M,KDIM] @ Bt[Nld,KDIM]^T + bias ----
// LDS staging via global_load_lds width=16; BK=64 doubles bytes-in-flight per
// barrier round (36 rounds instead of 72) to attack HBM-latency serialization.
template<bool RELU, bool OUTBF16>
__global__ __launch_bounds__(256) void k_gemm(
    const unsigned short* __restrict__ Ag, const unsigned short* __restrict__ Bg,
    const float* __restrict__ bias, void* __restrict__ outp,
    int Nld, int Mreal) {
  __shared__ unsigned short As[128 * 64];   // 16 KB
  __shared__ unsigned short Bs[128 * 64];   // 16 KB
  const int t = threadIdx.x;
  const int m0 = blockIdx.x * 128;
  const int n0 = blockIdx.y * 128;
  const int lane = t & 63, wid = t >> 6;
  const int wm = (wid >> 1) * 64, wn = (wid & 1) * 64;
  const int c15 = lane & 15, quad = lane >> 4;

  f32x4 acc[4][4];
#pragma unroll
  for (int i = 0; i < 4; i++)
#pragma unroll
    for (int j = 0; j < 4; j++) acc[i][j] = (f32x4)0.f;

  // staging: 4 chunks each for A and B; chunk j covers rows j*32..j*32+31
  int rowc[4], ccc[4];
#pragma unroll
  for (int j = 0; j < 4; j++) {
    int flat = j * 2048 + t * 8;        // shorts; lane*16B within each wave
    rowc[j] = flat >> 6;                // /64 cols
    ccc[j] = flat & 63;
  }

  for (int kt = 0; kt < KDIM; kt += 64) {   // KDIM = 36*64
#pragma unroll
    for (int j = 0; j < 4; j++) {
      int flat = j * 2048 + t * 8;
      GLOAD_LDS16(&Ag[(size_t)(m0 + rowc[j]) * KDIM + kt + ccc[j]], &As[flat]);
      GLOAD_LDS16(&Bg[(size_t)(n0 + rowc[j]) * KDIM + kt + ccc[j]], &Bs[flat]);
    }
    __syncthreads();
#pragma unroll
    for (int kk = 0; kk < 64; kk += 32) {
      short8 af[4], bf[4];
#pragma unroll
      for (int mi = 0; mi < 4; mi++)
        af[mi] = *(const short8*)&As[(wm + mi * 16 + c15) * 64 + kk + quad * 8];
#pragma unroll
      for (int ni = 0; ni < 4; ni++)
        bf[ni] = *(const short8*)&Bs[(wn + ni * 16 + c15) * 64 + kk + quad * 8];
#pragma unroll
      for (int mi = 0; mi < 4; mi++)
#pragma unroll
        for (int ni = 0; ni < 4; ni++)
          acc[mi][ni] = __builtin_amdgcn_mfma_f32_16x16x32_bf16(af[mi], bf[ni], acc[mi][ni], 0, 0, 0);
    }
    __syncthreads();
  }

#pragma unroll
  for (int mi = 0; mi < 4; mi++) {
#pragma unroll
    for (int ni = 0; ni < 4; ni++) {
      int n = n0 + wn + ni * 16 + c15;
      float bv = bias[n];
#pragma unroll
      for (int r = 0; r < 4; r++) {
        int m = m0 + wm + mi * 16 + quad * 4 + r;
        if (m < Mreal) {
          float v = acc[mi][ni][r] + bv;
          if (RELU) v = v > 0.f ? v : 0.f;
          if (OUTBF16) ((unsigned short*)outp)[(size_t)m * Nld + n] = f2bf(v);
          else         ((float*)outp)[(size_t)m * Nld + n] = v;
        }
      }
    }
  }
}

extern "C" void kernel_launch(void* const* d_in, const int* in_sizes, int n_in,
                              void* d_out, int out_size, void* d_ws, size_t ws_size,
                              hipStream_t stream) {
  const float* x     = (const float*)d_in[0];
  const int*   ei    = (const int*)d_in[1];   // [2, E]: src row then dst row
  const int*   et    = (const int*)d_in[2];   // [E]
  const float* W1    = (const float*)d_in[3]; // [2048,256]
  const float* root1 = (const float*)d_in[4]; // [256,256]
  const float* b1    = (const float*)d_in[5];
  const float* W2    = (const float*)d_in[6]; // [2048,128]
  const float* root2 = (const float*)d_in[7]; // [256,128]
  const float* b2    = (const float*)d_in[8];

  const int N = in_sizes[0] / F;              // 50000
  const int E = in_sizes[2];                  // 800000
  const int nbins = N * RELS;                 // 400000
  const int Mpad = ((N + 127) / 128) * 128;   // 50048
  const int nsb = (nbins + SCAN_CHUNK - 1) / SCAN_CHUNK;

  char* base = (char*)d_ws;
  size_t off = 0;
  auto alloc = [&](size_t bytes) {
    void* r = base + off;
    off = (off + bytes + 511) & ~(size_t)511;
    return r;
  };
  unsigned short* Wt1  = (unsigned short*)alloc((size_t)256 * KDIM * 2);
  unsigned short* Wt2  = (unsigned short*)alloc((size_t)128 * KDIM * 2);
  int*            cnt  = (int*)alloc((size_t)nbins * 4);
  int*            strt = (int*)alloc((size_t)(nbins + 1) * 4);
  int*            bsum = (int*)alloc((size_t)(nsb + 1) * 4);
  int*            ssrc = (int*)alloc((size_t)E * 4);
  // xh: single buffer aliased across lifetimes — layer-1 gather source
  // (bf16 x), then overwritten by GEMM1 as h, then layer-2 gather source.
  unsigned short* xh   = (unsigned short*)alloc((size_t)Mpad * F * 2);
  unsigned short* A    = (unsigned short*)alloc((size_t)Mpad * KDIM * 2);
  (void)ws_size; (void)n_in; (void)out_size;

  hipMemsetAsync(cnt, 0, (size_t)nbins * 4, stream);
  k_xb<<<(N * 64 + 255) / 256, 256, 0, stream>>>(x, xh, N);
  k_wt<<<(256 * KDIM + 255) / 256, 256, 0, stream>>>(W1, root1, Wt1, 256);
  k_wt<<<(128 * KDIM + 255) / 256, 256, 0, stream>>>(W2, root2, Wt2, 128);
  k_count<<<(E + 255) / 256, 256, 0, stream>>>(ei, et, cnt, E);
  k_scan1<<<nsb, 256, 0, stream>>>(cnt, strt, bsum, nbins);
  k_scan2<<<1, 1024, 0, stream>>>(bsum, nsb);
  k_scan3<<<(nbins + 255) / 256, 256, 0, stream>>>(strt, bsum, nbins, nsb);
  hipMemsetAsync(cnt, 0, (size_t)nbins * 4, stream);  // reuse as cursor
  k_scatter<<<(E + 255) / 256, 256, 0, stream>>>(ei, et, strt, cnt, ssrc, E);

  // Layer 1: gather from compact xh (bf16 x); A written nontemporal.
  // GEMM1 then overwrites xh with h (xh's x-copy is dead by that point).
  k_agg<<<(nbins + 3) / 4, 256, 0, stream>>>(xh, strt, ssrc, A, nbins);
  k_copy_nt<<<(N * 64 + 255) / 256, 256, 0, stream>>>(xh, A, N);
  k_gemm<true, true><<<dim3(Mpad / 128, 2), 256, 0, stream>>>(A, Wt1, b1, xh, 256, N);

  // Layer 2: gather from compact xh (now h).
  k_agg<<<(nbins + 3) / 4, 256, 0, stream>>>(xh, strt, ssrc, A, nbins);
  k_copy_nt<<<(N * 64 + 255) / 256, 256, 0, stream>>>(xh, A, N);
  k_gemm<false, false><<<dim3(Mpad / 128, 1), 256, 0, stream>>>(A, Wt2, b2, d_out, 128, N);
}

// Round 9
// 628.742 us; speedup vs baseline: 1.4216x; 1.0456x over previous
//
#include <hip/hip_runtime.h>
#include <stdint.h>

#define RELS 8
#define F 256
#define KDIM 2304        // 8*256 stacked relations + 256 root/self columns
#define NKT 36           // KDIM / 64 k-tiles
#define TSZ 8192         // shorts per (tile,kt) chunk: 128 rows x 64 cols
#define SCAN_CHUNK 1024  // bins per scan1 block (256 threads x 4)

// A/Wt global layout: tiled+swizzled. chunk(tile,kt) is contiguous 16KB:
//   addr = (tile*NKT + kt)*TSZ + row*64 + swz(unit,row)*8 + within
// where k = kt*64 + unit*8 + within (shorts), unit' = (unit+row)&7.
// LDS staging copies chunks verbatim, so LDS layout == global layout.

typedef __attribute__((ext_vector_type(8))) short short8;
typedef __attribute__((ext_vector_type(4))) float f32x4;
typedef __attribute__((ext_vector_type(2))) unsigned int uint2v;

__device__ __forceinline__ unsigned short f2bf(float f) {
  union { float f; unsigned int u; } v; v.f = f;
  unsigned int u = v.u;
  if ((u & 0x7f800000u) == 0x7f800000u) return (unsigned short)(u >> 16);
  return (unsigned short)((u + 0x7fffu + ((u >> 16) & 1u)) >> 16);  // RNE
}
__device__ __forceinline__ float bf2f(unsigned short b) {
  union { unsigned int u; float f; } v; v.u = ((unsigned int)b) << 16; return v.f;
}

// async 16B global -> LDS (wave-uniform base + lane*16)
#define GLOAD_LDS16(g, l)                                              \
  __builtin_amdgcn_global_load_lds(                                    \
      (const __attribute__((address_space(1))) void*)(g),              \
      (__attribute__((address_space(3))) void*)(l), 16, 0, 0)

// ---- x fp32 -> compact bf16 [N,256] (small L3-resident gather source)
__global__ void k_xb(const float* __restrict__ x, unsigned short* __restrict__ xb, int N) {
  int tid = blockIdx.x * blockDim.x + threadIdx.x;
  int n = tid >> 6, q = tid & 63;
  if (n >= N) return;
  const float4 v = *(const float4*)&x[(size_t)n * F + q * 4];
  ushort4 o;
  o.x = f2bf(v.x); o.y = f2bf(v.y); o.z = f2bf(v.z); o.w = f2bf(v.w);
  *(ushort4*)&xb[(size_t)n * F + q * 4] = o;
}

// ---- weight convert+transpose into tiled+swizzled layout ----
// Wt content: row n (output col), k<2048: W[k][n]; else root[k-2048][n].
__global__ void k_wt(const float* __restrict__ W, const float* __restrict__ root,
                     unsigned short* __restrict__ Wt, int Ncols) {
  int tid = blockIdx.x * blockDim.x + threadIdx.x;
  int total = Ncols * KDIM;
  if (tid >= total) return;
  int n = tid / KDIM, k = tid - n * KDIM;
  float v = (k < 2048) ? W[(size_t)k * Ncols + n] : root[(size_t)(k - 2048) * Ncols + n];
  int tile = n >> 7, row = n & 127;
  int kt = k >> 6, c = k & 63;
  int u = ((c >> 3) + row) & 7;
  Wt[(size_t)(tile * NKT + kt) * TSZ + row * 64 + u * 8 + (c & 7)] = f2bf(v);
}

// ---- CSR build ----
__global__ void k_count(const int* __restrict__ ei, const int* __restrict__ et,
                        int* __restrict__ cnt, int E) {
  int e = blockIdx.x * blockDim.x + threadIdx.x;
  if (e >= E) return;
  int bin = ei[E + e] * RELS + et[e];
  atomicAdd(&cnt[bin], 1);
}

__global__ void k_scan1(const int* __restrict__ cnt, int* __restrict__ start,
                        int* __restrict__ bsum, int nb) {
  __shared__ int tsum[256];
  const int t = threadIdx.x;
  const int idx = blockIdx.x * SCAN_CHUNK + t * 4;
  int v[4]; int s = 0;
#pragma unroll
  for (int i = 0; i < 4; i++) { v[i] = (idx + i < nb) ? cnt[idx + i] : 0; s += v[i]; }
  tsum[t] = s;
  __syncthreads();
  for (int d = 1; d < 256; d <<= 1) {
    int a = (t >= d) ? tsum[t - d] : 0;
    __syncthreads();
    tsum[t] += a;
    __syncthreads();
  }
  int ex = (t > 0) ? tsum[t - 1] : 0;
#pragma unroll
  for (int i = 0; i < 4; i++) { if (idx + i < nb) start[idx + i] = ex; ex += v[i]; }
  if (t == 255) bsum[blockIdx.x] = tsum[255];
}

__global__ void k_scan2(int* __restrict__ bsum, int nblocks) {
  __shared__ int sh[1024];
  const int t = threadIdx.x;
  sh[t] = (t < nblocks) ? bsum[t] : 0;
  __syncthreads();
  for (int d = 1; d < 1024; d <<= 1) {
    int a = (t >= d) ? sh[t - d] : 0;
    __syncthreads();
    sh[t] += a;
    __syncthreads();
  }
  if (t < nblocks) bsum[t] = (t > 0) ? sh[t - 1] : 0;
  if (t == 1023) bsum[nblocks] = sh[1023];
}

__global__ void k_scan3(int* __restrict__ start, const int* __restrict__ bsum,
                        int nb, int nblocks) {
  int i = blockIdx.x * blockDim.x + threadIdx.x;
  if (i < nb) start[i] += bsum[i >> 10];
  if (i == 0) start[nb] = bsum[nblocks];
}

__global__ void k_scatter(const int* __restrict__ ei, const int* __restrict__ et,
                          const int* __restrict__ start, int* __restrict__ cur,
                          int* __restrict__ ssrc, int E) {
  int e = blockIdx.x * blockDim.x + threadIdx.x;
  if (e >= E) return;
  int bin = ei[E + e] * RELS + et[e];
  int p = atomicAdd(&cur[bin], 1);
  ssrc[start[bin] + p] = ei[e];
}

// ---- aggregation: one wave per (dst, rel) bin; writes tiled+swizzled A ----
__global__ void k_agg(const unsigned short* __restrict__ src,
                      const int* __restrict__ start, const int* __restrict__ ssrc,
                      unsigned short* __restrict__ A, int nbins) {
  int w = blockIdx.x * 4 + (threadIdx.x >> 6);
  int lane = threadIdx.x & 63;
  if (w >= nbins) return;
  int s0 = start[w], s1 = start[w + 1];
  int deg = s1 - s0;
  float scale = 1.0f / (float)(deg > 1 ? deg : 1);
  float a0 = 0.f, a1 = 0.f, a2 = 0.f, a3 = 0.f;
  int e = s0;
  for (; e + 1 < s1; e += 2) {           // 2 outstanding gathers per wave
    int sA = ssrc[e], sB = ssrc[e + 1];
    const ushort4 vA = *(const ushort4*)&src[(size_t)sA * F + lane * 4];
    const ushort4 vB = *(const ushort4*)&src[(size_t)sB * F + lane * 4];
    a0 += bf2f(vA.x) + bf2f(vB.x); a1 += bf2f(vA.y) + bf2f(vB.y);
    a2 += bf2f(vA.z) + bf2f(vB.z); a3 += bf2f(vA.w) + bf2f(vB.w);
  }
  if (e < s1) {
    int sA = ssrc[e];
    const ushort4 vA = *(const ushort4*)&src[(size_t)sA * F + lane * 4];
    a0 += bf2f(vA.x); a1 += bf2f(vA.y); a2 += bf2f(vA.z); a3 += bf2f(vA.w);
  }
  int n = w >> 3, r = w & 7;
  int tile = n >> 7, row = n & 127;
  int kt = r * 4 + (lane >> 4);                 // k-chunk this lane's 4 shorts land in
  int u = (((lane & 15) >> 1) + row) & 7;       // swizzled 16B unit
  uint2v o;
  o.x = (unsigned)f2bf(a0 * scale) | ((unsigned)f2bf(a1 * scale) << 16);
  o.y = (unsigned)f2bf(a2 * scale) | ((unsigned)f2bf(a3 * scale) << 16);
  __builtin_nontemporal_store(o,
      (uint2v*)&A[(size_t)(tile * NKT + kt) * TSZ + row * 64 + u * 8 + (lane & 1) * 4]);
}

// ---- copy self features into A's last 256 K-cols (r=8 slice), tiled+swizzled ----
__global__ void k_copy_nt(const unsigned short* __restrict__ src, unsigned short* __restrict__ A, int N) {
  int tid = blockIdx.x * blockDim.x + threadIdx.x;
  int n = tid >> 6, q = tid & 63;
  if (n >= N) return;
  const uint2v v = *(const uint2v*)&src[(size_t)n * F + q * 4];
  int tile = n >> 7, row = n & 127;
  int kt = 32 + (q >> 4);
  int u = (((q & 15) >> 1) + row) & 7;
  __builtin_nontemporal_store(v,
      (uint2v*)&A[(size_t)(tile * NKT + kt) * TSZ + row * 64 + u * 8 + (q & 1) * 4]);
}

// ---- 128x128 bf16 MFMA GEMM over tiled+swizzled A/B ----
// Each K-round stages one contiguous 16KB A-chunk + 16KB B-chunk (sequential
// HBM bursts). Swizzle kills LDS fragment-read bank conflicts.
template<bool RELU, bool OUTBF16>
__global__ __launch_bounds__(256) void k_gemm(
    const unsigned short* __restrict__ Ag, const unsigned short* __restrict__ Bg,
    const float* __restrict__ bias, void* __restrict__ outp,
    int Nld, int Mreal) {
  __shared__ unsigned short As[TSZ];   // 16 KB
  __shared__ unsigned short Bs[TSZ];   // 16 KB
  const int t = threadIdx.x;
  const int m0 = blockIdx.x * 128;
  const int n0 = blockIdx.y * 128;
  const int lane = t & 63, wid = t >> 6;
  const int wm = (wid >> 1) * 64, wn = (wid & 1) * 64;
  const int c15 = lane & 15, quad = lane >> 4;

  f32x4 acc[4][4];
#pragma unroll
  for (int i = 0; i < 4; i++)
#pragma unroll
    for (int j = 0; j < 4; j++) acc[i][j] = (f32x4)0.f;

  const unsigned short* Abase = Ag + (size_t)blockIdx.x * NKT * TSZ;
  const unsigned short* Bbase = Bg + (size_t)blockIdx.y * NKT * TSZ;

  for (int kt = 0; kt < NKT; kt++) {
    const unsigned short* ac = Abase + (size_t)kt * TSZ;
    const unsigned short* bc = Bbase + (size_t)kt * TSZ;
#pragma unroll
    for (int j = 0; j < 4; j++) {
      GLOAD_LDS16(ac + j * 2048 + t * 8, &As[j * 2048 + t * 8]);
      GLOAD_LDS16(bc + j * 2048 + t * 8, &Bs[j * 2048 + t * 8]);
    }
    __syncthreads();
#pragma unroll
    for (int kk = 0; kk < 2; kk++) {          // two 32-k halves of the 64-k chunk
      short8 af[4], bf[4];
#pragma unroll
      for (int mi = 0; mi < 4; mi++) {
        int row = wm + mi * 16 + c15;
        int u = ((kk * 4 + quad) + row) & 7;
        af[mi] = *(const short8*)&As[row * 64 + u * 8];
      }
#pragma unroll
      for (int ni = 0; ni < 4; ni++) {
        int row = wn + ni * 16 + c15;
        int u = ((kk * 4 + quad) + row) & 7;
        bf[ni] = *(const short8*)&Bs[row * 64 + u * 8];
      }
#pragma unroll
      for (int mi = 0; mi < 4; mi++)
#pragma unroll
        for (int ni = 0; ni < 4; ni++)
          acc[mi][ni] = __builtin_amdgcn_mfma_f32_16x16x32_bf16(af[mi], bf[ni], acc[mi][ni], 0, 0, 0);
    }
    __syncthreads();
  }

#pragma unroll
  for (int mi = 0; mi < 4; mi++) {
#pragma unroll
    for (int ni = 0; ni < 4; ni++) {
      int n = n0 + wn + ni * 16 + c15;
      float bv = bias[n];
#pragma unroll
      for (int r = 0; r < 4; r++) {
        int m = m0 + wm + mi * 16 + quad * 4 + r;
        if (m < Mreal) {
          float v = acc[mi][ni][r] + bv;
          if (RELU) v = v > 0.f ? v : 0.f;
          if (OUTBF16) ((unsigned short*)outp)[(size_t)m * Nld + n] = f2bf(v);
          else         ((float*)outp)[(size_t)m * Nld + n] = v;
        }
      }
    }
  }
}

extern "C" void kernel_launch(void* const* d_in, const int* in_sizes, int n_in,
                              void* d_out, int out_size, void* d_ws, size_t ws_size,
                              hipStream_t stream) {
  const float* x     = (const float*)d_in[0];
  const int*   ei    = (const int*)d_in[1];   // [2, E]: src row then dst row
  const int*   et    = (const int*)d_in[2];   // [E]
  const float* W1    = (const float*)d_in[3]; // [2048,256]
  const float* root1 = (const float*)d_in[4]; // [256,256]
  const float* b1    = (const float*)d_in[5];
  const float* W2    = (const float*)d_in[6]; // [2048,128]
  const float* root2 = (const float*)d_in[7]; // [256,128]
  const float* b2    = (const float*)d_in[8];

  const int N = in_sizes[0] / F;              // 50000
  const int E = in_sizes[2];                  // 800000
  const int nbins = N * RELS;                 // 400000
  const int Mpad = ((N + 127) / 128) * 128;   // 50048
  const int ntiles = Mpad / 128;              // 391
  const int nsb = (nbins + SCAN_CHUNK - 1) / SCAN_CHUNK;

  char* base = (char*)d_ws;
  size_t off = 0;
  auto alloc = [&](size_t bytes) {
    void* r = base + off;
    off = (off + bytes + 511) & ~(size_t)511;
    return r;
  };
  unsigned short* Wt1  = (unsigned short*)alloc((size_t)2 * NKT * TSZ * 2);  // 256 cols
  unsigned short* Wt2  = (unsigned short*)alloc((size_t)1 * NKT * TSZ * 2);  // 128 cols
  int*            cnt  = (int*)alloc((size_t)nbins * 4);
  int*            strt = (int*)alloc((size_t)(nbins + 1) * 4);
  int*            bsum = (int*)alloc((size_t)(nsb + 1) * 4);
  int*            ssrc = (int*)alloc((size_t)E * 4);
  // xh: single buffer aliased across lifetimes — layer-1 gather source
  // (bf16 x), then overwritten by GEMM1 as h, then layer-2 gather source.
  unsigned short* xh   = (unsigned short*)alloc((size_t)Mpad * F * 2);
  unsigned short* A    = (unsigned short*)alloc((size_t)ntiles * NKT * TSZ * 2);
  (void)ws_size; (void)n_in; (void)out_size;

  hipMemsetAsync(cnt, 0, (size_t)nbins * 4, stream);
  k_xb<<<(N * 64 + 255) / 256, 256, 0, stream>>>(x, xh, N);
  k_wt<<<(256 * KDIM + 255) / 256, 256, 0, stream>>>(W1, root1, Wt1, 256);
  k_wt<<<(128 * KDIM + 255) / 256, 256, 0, stream>>>(W2, root2, Wt2, 128);
  k_count<<<(E + 255) / 256, 256, 0, stream>>>(ei, et, cnt, E);
  k_scan1<<<nsb, 256, 0, stream>>>(cnt, strt, bsum, nbins);
  k_scan2<<<1, 1024, 0, stream>>>(bsum, nsb);
  k_scan3<<<(nbins + 255) / 256, 256, 0, stream>>>(strt, bsum, nbins, nsb);
  hipMemsetAsync(cnt, 0, (size_t)nbins * 4, stream);  // reuse as cursor
  k_scatter<<<(E + 255) / 256, 256, 0, stream>>>(ei, et, strt, cnt, ssrc, E);

  // Layer 1: gather from compact xh (bf16 x); A written nontemporal (tiled).
  // GEMM1 then overwrites xh with h (xh's x-copy is dead by that point).
  k_agg<<<(nbins + 3) / 4, 256, 0, stream>>>(xh, strt, ssrc, A, nbins);
  k_copy_nt<<<(N * 64 + 255) / 256, 256, 0, stream>>>(xh, A, N);
  k_gemm<true, true><<<dim3(ntiles, 2), 256, 0, stream>>>(A, Wt1, b1, xh, 256, N);

  // Layer 2: gather from compact xh (now h).
  k_agg<<<(nbins + 3) / 4, 256, 0, stream>>>(xh, strt, ssrc, A, nbins);
  k_copy_nt<<<(N * 64 + 255) / 256, 256, 0, stream>>>(xh, A, N);
  k_gemm<false, false><<<dim3(ntiles, 1), 256, 0, stream>>>(A, Wt2, b2, d_out, 128, N);
}